// Round 8
// baseline (291.933 us; speedup 1.0000x reference)
//
#include <hip/hip_runtime.h>
#include <hip/hip_bf16.h>
#include <cstdint>
#include <cstddef>

#define NNODES 50000
#define NEDGES 800000
#define DF 64
#define KM 192      // msg MLP input dim (3*D)
#define KU 128      // upd MLP input dim (2*D)
#define SROW 264    // LDS row stride in bf16 elems (528 B, 16B-aligned; 528%128=16 -> phased banks)

typedef __bf16 bf16_t;
typedef __bf16 bf16x8 __attribute__((ext_vector_type(8)));
typedef __bf16 bf16x4 __attribute__((ext_vector_type(4)));
typedef float  f32x4  __attribute__((ext_vector_type(4)));

// ---------------------------------------------------------------------------
// Weight packing: W[K][N] fp32 row-major -> bf16 MFMA B-fragments.
// Fragment (kblk, ct): lane l, elem j holds W[kblk*32 + (l>>4)*8 + j][ct*16 + (l&15)]
// Flat: ((kblk*(N/16) + ct)*64 + l)*8 + j.
// Segments: Wm1 @0 (49152), Wm2 @49152 (16384), Wu1 @65536 (32768), Wu2 @98304 (16384).
// ---------------------------------------------------------------------------
__global__ void prep_kernel(const float* __restrict__ Wm1, const float* __restrict__ Wm2,
                            const float* __restrict__ Wu1, const float* __restrict__ Wu2,
                            bf16_t* __restrict__ wp)
{
    int idx = blockIdx.x * 256 + threadIdx.x;
    const float* src; int N; int off; int local;
    if (idx < 49152)       { src = Wm1; N = 256; off = 0;     local = idx; }
    else if (idx < 65536)  { src = Wm2; N = 64;  off = 49152; local = idx - 49152; }
    else if (idx < 98304)  { src = Wu1; N = 256; off = 65536; local = idx - 65536; }
    else if (idx < 114688) { src = Wu2; N = 64;  off = 98304; local = idx - 98304; }
    else return;
    int j    = local & 7;
    int l    = (local >> 3) & 63;
    int frag = local >> 9;
    int nct  = N >> 4;
    int kblk = frag / nct;
    int ct   = frag - kblk * nct;
    int k = kblk * 32 + (l >> 4) * 8 + j;
    int n = ct * 16 + (l & 15);
    wp[off + local] = (bf16_t)src[(size_t)k * N + n];
}

__device__ __forceinline__ void st_bf16x4(bf16_t* p, float4 v) {
    bf16x4 bv;
    bv[0] = (bf16_t)v.x; bv[1] = (bf16_t)v.y; bv[2] = (bf16_t)v.z; bv[3] = (bf16_t)v.w;
    *reinterpret_cast<bf16x4*>(p) = bv;
}

// ---------------------------------------------------------------------------
// Message kernel: 128 edges/block, 1024 threads (16 waves), 2D wave grid.
// Layer1 (128x192 @ 192x256): wave (wm = w>>3, wn = w&7) owns
//   edges [wm*64, wm*64+64) x cols [wn*32, wn*32+32)   (4 A-frags x 2 ct)
//   -> each A-frag LDS read feeds 2 MFMAs: A-reads 768 -> 384 b128/block vs r7;
//      B-loads 96 -> 192 (global, L2-hot -- different pipe than LDS).
// Layer2 (128x256 @ 256x64): wave (m4 = w>>2, ct2 = w&3) owns
//   edges [m4*32,+32) x cols [ct2*16,+16): 2 A-frags, acc2 = 8 regs.
// acc = 32 AGPR; single live a-frag in inner loop targets <=64-ish unified regs.
// launch_bounds(1024,4): VGPR cap 128 -> zero spill risk (r4 lesson).
// ---------------------------------------------------------------------------
__global__ __launch_bounds__(1024, 4)
void msg_kernel(const float* __restrict__ h, const float* __restrict__ efeat,
                const int* __restrict__ snd, const int* __restrict__ rcv,
                const bf16_t* __restrict__ Wp1, const float* __restrict__ b1,
                const bf16_t* __restrict__ Wp2, const float* __restrict__ b2,
                float* __restrict__ agg)
{
    __shared__ bf16_t s_buf[128 * SROW];   // 67584 B
    __shared__ int s_snd[128];
    __shared__ int s_rcv[128];

    const int t  = threadIdx.x;
    const int e0 = blockIdx.x * 128;

    if (t < 128)      s_snd[t]       = snd[e0 + t];
    else if (t < 256) s_rcv[t - 128] = rcv[e0 + t - 128];

    // e-segment (no idx dependency): 128 rows x 16 float4 = 2048, 2 iters of 1024
    #pragma unroll
    for (int it = 0; it < 2; ++it) {
        int i = t + it * 1024; int row = i >> 4; int col = (i & 15) * 4;
        float4 v = *reinterpret_cast<const float4*>(efeat + (size_t)(e0 + row) * DF + col);
        st_bf16x4(&s_buf[row * SROW + col], v);
    }
    __syncthreads();   // idx visible (e-writes touch a disjoint LDS region)

    #pragma unroll
    for (int it = 0; it < 2; ++it) {
        int i = t + it * 1024; int row = i >> 4; int col = (i & 15) * 4;
        float4 v = *reinterpret_cast<const float4*>(h + (size_t)s_snd[row] * DF + col);
        st_bf16x4(&s_buf[row * SROW + DF + col], v);
    }
    #pragma unroll
    for (int it = 0; it < 2; ++it) {
        int i = t + it * 1024; int row = i >> 4; int col = (i & 15) * 4;
        float4 v = *reinterpret_cast<const float4*>(h + (size_t)s_rcv[row] * DF + col);
        st_bf16x4(&s_buf[row * SROW + 2 * DF + col], v);
    }
    __syncthreads();

    const int w = t >> 6;      // wave 0..15
    const int l = t & 63;
    const int q = l >> 4;
    const int r = l & 15;

    // ---- layer 1: wave (wm, wn): 64 edges x 32 cols ----
    const int wm = w >> 3;     // edge half
    const int wn = w & 7;      // col pair (2 ct)
    f32x4 acc[2][4];           // [g][am]
    #pragma unroll
    for (int g = 0; g < 2; ++g)
        #pragma unroll
        for (int am = 0; am < 4; ++am) acc[g][am] = (f32x4){0.f, 0.f, 0.f, 0.f};

    #pragma unroll
    for (int kb = 0; kb < 6; ++kb) {
        bf16x8 b0 = *reinterpret_cast<const bf16x8*>(Wp1 + ((size_t)(kb * 16 + wn * 2 + 0) * 64 + l) * 8);
        bf16x8 b1f = *reinterpret_cast<const bf16x8*>(Wp1 + ((size_t)(kb * 16 + wn * 2 + 1) * 64 + l) * 8);
        #pragma unroll
        for (int am = 0; am < 4; ++am) {
            bf16x8 a = *reinterpret_cast<const bf16x8*>(
                &s_buf[(wm * 64 + am * 16 + r) * SROW + kb * 32 + q * 8]);
            acc[0][am] = __builtin_amdgcn_mfma_f32_16x16x32_bf16(a, b0,  acc[0][am], 0, 0, 0);
            acc[1][am] = __builtin_amdgcn_mfma_f32_16x16x32_bf16(a, b1f, acc[1][am], 0, 0, 0);
        }
    }
    __syncthreads();   // all waves done reading the input tile

    // bias + relu -> c1 into s_buf (row = edge, col = hidden unit)
    #pragma unroll
    for (int g = 0; g < 2; ++g) {
        const int col1 = (wn * 2 + g) * 16 + r;
        const float bias1 = b1[col1];
        #pragma unroll
        for (int am = 0; am < 4; ++am)
            #pragma unroll
            for (int j = 0; j < 4; ++j)
                s_buf[(wm * 64 + am * 16 + q * 4 + j) * SROW + col1] =
                    (bf16_t)fmaxf(acc[g][am][j] + bias1, 0.f);
    }
    __syncthreads();   // c1 complete

    // ---- layer 2: wave (m4 = w>>2, ct2 = w&3): 32 edges x 16 cols ----
    const int m4  = w >> 2;
    const int ct2 = w & 3;
    f32x4 acc2[2];
    #pragma unroll
    for (int am = 0; am < 2; ++am) acc2[am] = (f32x4){0.f, 0.f, 0.f, 0.f};

    #pragma unroll
    for (int kb = 0; kb < 8; ++kb) {
        bf16x8 b = *reinterpret_cast<const bf16x8*>(Wp2 + ((size_t)(kb * 4 + ct2) * 64 + l) * 8);
        #pragma unroll
        for (int am = 0; am < 2; ++am) {
            bf16x8 a = *reinterpret_cast<const bf16x8*>(
                &s_buf[(m4 * 32 + am * 16 + r) * SROW + kb * 32 + q * 8]);
            acc2[am] = __builtin_amdgcn_mfma_f32_16x16x32_bf16(a, b, acc2[am], 0, 0, 0);
        }
    }

    // scatter (+bias): 8 fp32 atomics/thread, 64B-contiguous per 16-lane group
    const float bias2 = b2[ct2 * 16 + r];
    #pragma unroll
    for (int am = 0; am < 2; ++am)
        #pragma unroll
        for (int j = 0; j < 4; ++j) {
            int erow = m4 * 32 + am * 16 + q * 4 + j;
            atomicAdd(agg + (size_t)s_rcv[erow] * DF + ct2 * 16 + r, acc2[am][j] + bias2);
        }
}

// ---------------------------------------------------------------------------
// Node-update kernel: r3/r6/r7's proven version (64 nodes/block, 4 waves, N-split).
// Alias-safe when agg==out: agg reads happen only in the gather (pre-barrier);
// stores come after the final barrier.
// ---------------------------------------------------------------------------
__global__ __launch_bounds__(256, 4)
void upd_kernel(const float* __restrict__ h, const float* __restrict__ agg,
                const bf16_t* __restrict__ Wp1, const float* __restrict__ b1,
                const bf16_t* __restrict__ Wp2, const float* __restrict__ b2,
                float* __restrict__ out)
{
    __shared__ bf16_t s_buf[64 * SROW];

    const int t  = threadIdx.x;
    const int n0 = blockIdx.x * 64;

    // gather u_in = [h | agg] : 64 rows x 128 cols
    #pragma unroll
    for (int it = 0; it < 8; ++it) {
        int i    = t + it * 256;       // < 2048 = 64*32
        int nn   = i >> 5;
        int col  = (i & 31) * 4;
        int node = n0 + nn;
        float4 v;
        if (node < NNODES) {
            const float* srcp = (col < DF) ? (h + (size_t)node * DF + col)
                                           : (agg + (size_t)node * DF + (col - DF));
            v = *reinterpret_cast<const float4*>(srcp);
        } else {
            v.x = 0.f; v.y = 0.f; v.z = 0.f; v.w = 0.f;
        }
        st_bf16x4(&s_buf[nn * SROW + col], v);
    }
    __syncthreads();

    const int w = t >> 6;
    const int l = t & 63;
    const int q = l >> 4;
    const int r = l & 15;

    f32x4 acc[4][4];
    #pragma unroll
    for (int g = 0; g < 4; ++g)
        #pragma unroll
        for (int am = 0; am < 4; ++am) acc[g][am] = (f32x4){0.f, 0.f, 0.f, 0.f};

    #pragma unroll
    for (int kb = 0; kb < 4; ++kb) {
        bf16x8 a[4];
        #pragma unroll
        for (int am = 0; am < 4; ++am)
            a[am] = *reinterpret_cast<const bf16x8*>(&s_buf[(am * 16 + r) * SROW + kb * 32 + q * 8]);
        #pragma unroll
        for (int g = 0; g < 4; ++g) {
            int ct = w * 4 + g;
            bf16x8 b = *reinterpret_cast<const bf16x8*>(Wp1 + ((size_t)(kb * 16 + ct) * 64 + l) * 8);
            #pragma unroll
            for (int am = 0; am < 4; ++am)
                acc[g][am] = __builtin_amdgcn_mfma_f32_16x16x32_bf16(a[am], b, acc[g][am], 0, 0, 0);
        }
    }
    __syncthreads();

    #pragma unroll
    for (int g = 0; g < 4; ++g) {
        int col = (w * 4 + g) * 16 + r;
        float bias = b1[col];
        #pragma unroll
        for (int am = 0; am < 4; ++am)
            #pragma unroll
            for (int j = 0; j < 4; ++j)
                s_buf[(am * 16 + q * 4 + j) * SROW + col] =
                    (bf16_t)fmaxf(acc[g][am][j] + bias, 0.f);
    }
    __syncthreads();

    f32x4 acc2[4];
    #pragma unroll
    for (int am = 0; am < 4; ++am) acc2[am] = (f32x4){0.f, 0.f, 0.f, 0.f};

    #pragma unroll
    for (int kb = 0; kb < 8; ++kb) {
        bf16x8 a[4];
        #pragma unroll
        for (int am = 0; am < 4; ++am)
            a[am] = *reinterpret_cast<const bf16x8*>(&s_buf[(am * 16 + r) * SROW + kb * 32 + q * 8]);
        bf16x8 b = *reinterpret_cast<const bf16x8*>(Wp2 + ((size_t)(kb * 4 + w) * 64 + l) * 8);
        #pragma unroll
        for (int am = 0; am < 4; ++am)
            acc2[am] = __builtin_amdgcn_mfma_f32_16x16x32_bf16(a[am], b, acc2[am], 0, 0, 0);
    }

    // residual store: out = h + dh  (col = w*16 + r)
    float bias2 = b2[w * 16 + r];
    #pragma unroll
    for (int am = 0; am < 4; ++am)
        #pragma unroll
        for (int j = 0; j < 4; ++j) {
            int node = n0 + am * 16 + q * 4 + j;
            if (node < NNODES) {
                int col = w * 16 + r;
                out[(size_t)node * DF + col] =
                    h[(size_t)node * DF + col] + acc2[am][j] + bias2;
            }
        }
}

extern "C" void kernel_launch(void* const* d_in, const int* in_sizes, int n_in,
                              void* d_out, int out_size, void* d_ws, size_t ws_size,
                              hipStream_t stream)
{
    const float* h    = (const float*)d_in[0];
    const float* e    = (const float*)d_in[1];
    const int*   snd  = (const int*)d_in[2];
    const int*   rcv  = (const int*)d_in[3];
    const float* W_m1 = (const float*)d_in[4];
    const float* b_m1 = (const float*)d_in[5];
    const float* W_m2 = (const float*)d_in[6];
    const float* b_m2 = (const float*)d_in[7];
    const float* W_u1 = (const float*)d_in[8];
    const float* b_u1 = (const float*)d_in[9];
    const float* W_u2 = (const float*)d_in[10];
    const float* b_u2 = (const float*)d_in[11];
    float* out = (float*)d_out;

    const size_t agg_bytes = (size_t)NNODES * DF * sizeof(float);   // 12.8 MB
    const size_t wp_bytes  = 114688 * sizeof(bf16_t);               // 229 KB

    float*  agg;
    bf16_t* wp;
    if (ws_size >= agg_bytes + wp_bytes) {
        agg = (float*)d_ws;
        wp  = (bf16_t*)((char*)d_ws + agg_bytes);
    } else {
        agg = out;               // alias-safe per upd_kernel structure
        wp  = (bf16_t*)d_ws;
    }

    bf16_t* Wp_m1 = wp;
    bf16_t* Wp_m2 = wp + 49152;
    bf16_t* Wp_u1 = wp + 65536;
    bf16_t* Wp_u2 = wp + 98304;

    prep_kernel<<<448, 256, 0, stream>>>(W_m1, W_m2, W_u1, W_u2, wp);
    hipMemsetAsync(agg, 0, agg_bytes, stream);

    msg_kernel<<<NEDGES / 128, 1024, 0, stream>>>(h, e, snd, rcv,
                                                  Wp_m1, b_m1, Wp_m2, b_m2, agg);
    upd_kernel<<<(NNODES + 63) / 64, 256, 0, stream>>>(h, agg,
                                                       Wp_u1, b_u1, Wp_u2, b_u2, out);
}

// Round 9
// 264.567 us; speedup vs baseline: 1.1034x; 1.1034x over previous
//
#include <hip/hip_runtime.h>
#include <hip/hip_bf16.h>
#include <cstdint>
#include <cstddef>

#define NNODES 50000
#define NEDGES 800000
#define DF 64
#define KM 192      // msg MLP input dim (3*D)
#define KU 128      // upd MLP input dim (2*D)
#define SROW 264    // LDS row stride in bf16 elems (528 B, 16B-aligned)

typedef __bf16 bf16_t;
typedef __bf16 bf16x8 __attribute__((ext_vector_type(8)));
typedef __bf16 bf16x4 __attribute__((ext_vector_type(4)));
typedef float  f32x4  __attribute__((ext_vector_type(4)));

// ---------------------------------------------------------------------------
// Weight packing: W[K][N] fp32 row-major -> bf16 MFMA B-fragments.
// Fragment (kblk, ct): lane l, elem j holds W[kblk*32 + (l>>4)*8 + j][ct*16 + (l&15)]
// Flat: ((kblk*(N/16) + ct)*64 + l)*8 + j.
// Segments: Wm1 @0 (49152), Wm2 @49152 (16384), Wu1 @65536 (32768), Wu2 @98304 (16384).
// ---------------------------------------------------------------------------
__global__ void prep_kernel(const float* __restrict__ Wm1, const float* __restrict__ Wm2,
                            const float* __restrict__ Wu1, const float* __restrict__ Wu2,
                            bf16_t* __restrict__ wp)
{
    int idx = blockIdx.x * 256 + threadIdx.x;
    const float* src; int N; int off; int local;
    if (idx < 49152)       { src = Wm1; N = 256; off = 0;     local = idx; }
    else if (idx < 65536)  { src = Wm2; N = 64;  off = 49152; local = idx - 49152; }
    else if (idx < 98304)  { src = Wu1; N = 256; off = 65536; local = idx - 65536; }
    else if (idx < 114688) { src = Wu2; N = 64;  off = 98304; local = idx - 98304; }
    else return;
    int j    = local & 7;
    int l    = (local >> 3) & 63;
    int frag = local >> 9;
    int nct  = N >> 4;
    int kblk = frag / nct;
    int ct   = frag - kblk * nct;
    int k = kblk * 32 + (l >> 4) * 8 + j;
    int n = ct * 16 + (l & 15);
    wp[off + local] = (bf16_t)src[(size_t)k * N + n];
}

__device__ __forceinline__ void st_bf16x4(bf16_t* p, float4 v) {
    bf16x4 bv;
    bv[0] = (bf16_t)v.x; bv[1] = (bf16_t)v.y; bv[2] = (bf16_t)v.z; bv[3] = (bf16_t)v.w;
    *reinterpret_cast<bf16x4*>(p) = bv;
}

// ---------------------------------------------------------------------------
// Message kernel: 128 edges/block, 512 threads (8 waves), 2D wave grids.
// Layer1 (128x192 @ 192x256): wave (wm = w>>2, wn = w&3) owns
//   edges [wm*64,+64) x cols [wn*64,+64)  -> 4 A-frags x 4 ct, acc[4][4]=64 AGPR.
//   Each A-frag feeds 4 MFMAs: A-reads 384 -> 192 b128/block vs r6.
// Layer2 (128x256 @ 256x64): wave (m4 = w>>1, n2 = w&1) owns
//   edges [m4*32,+32) x cols [n2*32,+32) -> 2 A-frags x 2 ct, acc2[2][2]=16.
//   A-reads 256 -> 128 b128/block.
// 512-thr blocks keep 2 blocks/CU (r8 lesson: single-block CUs drain at
// every barrier). 3 barriers (idx merged into e-gather phase, r7 trick).
// ---------------------------------------------------------------------------
__global__ __launch_bounds__(512, 4)
void msg_kernel(const float* __restrict__ h, const float* __restrict__ efeat,
                const int* __restrict__ snd, const int* __restrict__ rcv,
                const bf16_t* __restrict__ Wp1, const float* __restrict__ b1,
                const bf16_t* __restrict__ Wp2, const float* __restrict__ b2,
                float* __restrict__ agg)
{
    __shared__ bf16_t s_buf[128 * SROW];   // 67584 B
    __shared__ int s_snd[128];
    __shared__ int s_rcv[128];

    const int t  = threadIdx.x;
    const int e0 = blockIdx.x * 128;

    if (t < 128)      s_snd[t]       = snd[e0 + t];
    else if (t < 256) s_rcv[t - 128] = rcv[e0 + t - 128];

    // e-segment (no idx dependency): 128 rows x 16 float4 = 2048, 4 iters of 512
    #pragma unroll
    for (int it = 0; it < 4; ++it) {
        int i = t + it * 512; int row = i >> 4; int col = (i & 15) * 4;
        float4 v = *reinterpret_cast<const float4*>(efeat + (size_t)(e0 + row) * DF + col);
        st_bf16x4(&s_buf[row * SROW + col], v);
    }
    __syncthreads();   // idx visible (e-writes touch a disjoint LDS region)

    #pragma unroll
    for (int it = 0; it < 4; ++it) {
        int i = t + it * 512; int row = i >> 4; int col = (i & 15) * 4;
        float4 v = *reinterpret_cast<const float4*>(h + (size_t)s_snd[row] * DF + col);
        st_bf16x4(&s_buf[row * SROW + DF + col], v);
    }
    #pragma unroll
    for (int it = 0; it < 4; ++it) {
        int i = t + it * 512; int row = i >> 4; int col = (i & 15) * 4;
        float4 v = *reinterpret_cast<const float4*>(h + (size_t)s_rcv[row] * DF + col);
        st_bf16x4(&s_buf[row * SROW + 2 * DF + col], v);
    }
    __syncthreads();

    const int w = t >> 6;      // wave 0..7
    const int l = t & 63;
    const int q = l >> 4;
    const int r = l & 15;

    // ---- layer 1: wave (wm, wn): 64 edges x 64 cols ----
    const int wm = w >> 2;     // edge half (0/1)
    const int wn = w & 3;      // 64-col tile (4 ct)
    f32x4 acc[4][4];           // [g][am]
    #pragma unroll
    for (int g = 0; g < 4; ++g)
        #pragma unroll
        for (int am = 0; am < 4; ++am) acc[g][am] = (f32x4){0.f, 0.f, 0.f, 0.f};

    #pragma unroll
    for (int kb = 0; kb < 6; ++kb) {
        bf16x8 bfr[4];
        #pragma unroll
        for (int g = 0; g < 4; ++g)
            bfr[g] = *reinterpret_cast<const bf16x8*>(Wp1 + ((size_t)(kb * 16 + wn * 4 + g) * 64 + l) * 8);
        #pragma unroll
        for (int am = 0; am < 4; ++am) {
            bf16x8 a = *reinterpret_cast<const bf16x8*>(
                &s_buf[(wm * 64 + am * 16 + r) * SROW + kb * 32 + q * 8]);
            #pragma unroll
            for (int g = 0; g < 4; ++g)
                acc[g][am] = __builtin_amdgcn_mfma_f32_16x16x32_bf16(a, bfr[g], acc[g][am], 0, 0, 0);
        }
    }
    __syncthreads();   // all waves done reading the input tile

    // bias + relu -> c1 into s_buf (row = edge, col = hidden unit)
    #pragma unroll
    for (int g = 0; g < 4; ++g) {
        const int col1 = (wn * 4 + g) * 16 + r;
        const float bias1 = b1[col1];
        #pragma unroll
        for (int am = 0; am < 4; ++am)
            #pragma unroll
            for (int j = 0; j < 4; ++j)
                s_buf[(wm * 64 + am * 16 + q * 4 + j) * SROW + col1] =
                    (bf16_t)fmaxf(acc[g][am][j] + bias1, 0.f);
    }
    __syncthreads();   // c1 complete

    // ---- layer 2: wave (m4 = w>>1, n2 = w&1): 32 edges x 32 cols ----
    const int m4 = w >> 1;
    const int n2 = w & 1;
    f32x4 acc2[2][2];          // [g][am]
    #pragma unroll
    for (int g = 0; g < 2; ++g)
        #pragma unroll
        for (int am = 0; am < 2; ++am) acc2[g][am] = (f32x4){0.f, 0.f, 0.f, 0.f};

    #pragma unroll
    for (int kb = 0; kb < 8; ++kb) {
        bf16x8 b2f[2];
        #pragma unroll
        for (int g = 0; g < 2; ++g)
            b2f[g] = *reinterpret_cast<const bf16x8*>(Wp2 + ((size_t)(kb * 4 + n2 * 2 + g) * 64 + l) * 8);
        #pragma unroll
        for (int am = 0; am < 2; ++am) {
            bf16x8 a = *reinterpret_cast<const bf16x8*>(
                &s_buf[(m4 * 32 + am * 16 + r) * SROW + kb * 32 + q * 8]);
            #pragma unroll
            for (int g = 0; g < 2; ++g)
                acc2[g][am] = __builtin_amdgcn_mfma_f32_16x16x32_bf16(a, b2f[g], acc2[g][am], 0, 0, 0);
        }
    }

    // scatter (+bias): 16 fp32 atomics/thread, 64B-contiguous per 16-lane group
    #pragma unroll
    for (int g = 0; g < 2; ++g) {
        const int col = (n2 * 2 + g) * 16 + r;
        const float bias2 = b2[col];
        #pragma unroll
        for (int am = 0; am < 2; ++am)
            #pragma unroll
            for (int j = 0; j < 4; ++j) {
                int erow = m4 * 32 + am * 16 + q * 4 + j;
                atomicAdd(agg + (size_t)s_rcv[erow] * DF + col, acc2[g][am][j] + bias2);
            }
    }
}

// ---------------------------------------------------------------------------
// Node-update kernel: r3/r6/r7's proven version (64 nodes/block, 4 waves, N-split).
// Alias-safe when agg==out: agg reads happen only in the gather (pre-barrier);
// stores come after the final barrier.
// ---------------------------------------------------------------------------
__global__ __launch_bounds__(256, 4)
void upd_kernel(const float* __restrict__ h, const float* __restrict__ agg,
                const bf16_t* __restrict__ Wp1, const float* __restrict__ b1,
                const bf16_t* __restrict__ Wp2, const float* __restrict__ b2,
                float* __restrict__ out)
{
    __shared__ bf16_t s_buf[64 * SROW];

    const int t  = threadIdx.x;
    const int n0 = blockIdx.x * 64;

    // gather u_in = [h | agg] : 64 rows x 128 cols
    #pragma unroll
    for (int it = 0; it < 8; ++it) {
        int i    = t + it * 256;       // < 2048 = 64*32
        int nn   = i >> 5;
        int col  = (i & 31) * 4;
        int node = n0 + nn;
        float4 v;
        if (node < NNODES) {
            const float* srcp = (col < DF) ? (h + (size_t)node * DF + col)
                                           : (agg + (size_t)node * DF + (col - DF));
            v = *reinterpret_cast<const float4*>(srcp);
        } else {
            v.x = 0.f; v.y = 0.f; v.z = 0.f; v.w = 0.f;
        }
        st_bf16x4(&s_buf[nn * SROW + col], v);
    }
    __syncthreads();

    const int w = t >> 6;
    const int l = t & 63;
    const int q = l >> 4;
    const int r = l & 15;

    f32x4 acc[4][4];
    #pragma unroll
    for (int g = 0; g < 4; ++g)
        #pragma unroll
        for (int am = 0; am < 4; ++am) acc[g][am] = (f32x4){0.f, 0.f, 0.f, 0.f};

    #pragma unroll
    for (int kb = 0; kb < 4; ++kb) {
        bf16x8 a[4];
        #pragma unroll
        for (int am = 0; am < 4; ++am)
            a[am] = *reinterpret_cast<const bf16x8*>(&s_buf[(am * 16 + r) * SROW + kb * 32 + q * 8]);
        #pragma unroll
        for (int g = 0; g < 4; ++g) {
            int ct = w * 4 + g;
            bf16x8 b = *reinterpret_cast<const bf16x8*>(Wp1 + ((size_t)(kb * 16 + ct) * 64 + l) * 8);
            #pragma unroll
            for (int am = 0; am < 4; ++am)
                acc[g][am] = __builtin_amdgcn_mfma_f32_16x16x32_bf16(a[am], b, acc[g][am], 0, 0, 0);
        }
    }
    __syncthreads();

    #pragma unroll
    for (int g = 0; g < 4; ++g) {
        int col = (w * 4 + g) * 16 + r;
        float bias = b1[col];
        #pragma unroll
        for (int am = 0; am < 4; ++am)
            #pragma unroll
            for (int j = 0; j < 4; ++j)
                s_buf[(am * 16 + q * 4 + j) * SROW + col] =
                    (bf16_t)fmaxf(acc[g][am][j] + bias, 0.f);
    }
    __syncthreads();

    f32x4 acc2[4];
    #pragma unroll
    for (int am = 0; am < 4; ++am) acc2[am] = (f32x4){0.f, 0.f, 0.f, 0.f};

    #pragma unroll
    for (int kb = 0; kb < 8; ++kb) {
        bf16x8 a[4];
        #pragma unroll
        for (int am = 0; am < 4; ++am)
            a[am] = *reinterpret_cast<const bf16x8*>(&s_buf[(am * 16 + r) * SROW + kb * 32 + q * 8]);
        bf16x8 b = *reinterpret_cast<const bf16x8*>(Wp2 + ((size_t)(kb * 4 + w) * 64 + l) * 8);
        #pragma unroll
        for (int am = 0; am < 4; ++am)
            acc2[am] = __builtin_amdgcn_mfma_f32_16x16x32_bf16(a[am], b, acc2[am], 0, 0, 0);
    }

    // residual store: out = h + dh  (col = w*16 + r)
    float bias2 = b2[w * 16 + r];
    #pragma unroll
    for (int am = 0; am < 4; ++am)
        #pragma unroll
        for (int j = 0; j < 4; ++j) {
            int node = n0 + am * 16 + q * 4 + j;
            if (node < NNODES) {
                int col = w * 16 + r;
                out[(size_t)node * DF + col] =
                    h[(size_t)node * DF + col] + acc2[am][j] + bias2;
            }
        }
}

extern "C" void kernel_launch(void* const* d_in, const int* in_sizes, int n_in,
                              void* d_out, int out_size, void* d_ws, size_t ws_size,
                              hipStream_t stream)
{
    const float* h    = (const float*)d_in[0];
    const float* e    = (const float*)d_in[1];
    const int*   snd  = (const int*)d_in[2];
    const int*   rcv  = (const int*)d_in[3];
    const float* W_m1 = (const float*)d_in[4];
    const float* b_m1 = (const float*)d_in[5];
    const float* W_m2 = (const float*)d_in[6];
    const float* b_m2 = (const float*)d_in[7];
    const float* W_u1 = (const float*)d_in[8];
    const float* b_u1 = (const float*)d_in[9];
    const float* W_u2 = (const float*)d_in[10];
    const float* b_u2 = (const float*)d_in[11];
    float* out = (float*)d_out;

    const size_t agg_bytes = (size_t)NNODES * DF * sizeof(float);   // 12.8 MB
    const size_t wp_bytes  = 114688 * sizeof(bf16_t);               // 229 KB

    float*  agg;
    bf16_t* wp;
    if (ws_size >= agg_bytes + wp_bytes) {
        agg = (float*)d_ws;
        wp  = (bf16_t*)((char*)d_ws + agg_bytes);
    } else {
        agg = out;               // alias-safe per upd_kernel structure
        wp  = (bf16_t*)d_ws;
    }

    bf16_t* Wp_m1 = wp;
    bf16_t* Wp_m2 = wp + 49152;
    bf16_t* Wp_u1 = wp + 65536;
    bf16_t* Wp_u2 = wp + 98304;

    prep_kernel<<<448, 256, 0, stream>>>(W_m1, W_m2, W_u1, W_u2, wp);
    hipMemsetAsync(agg, 0, agg_bytes, stream);

    msg_kernel<<<NEDGES / 128, 512, 0, stream>>>(h, e, snd, rcv,
                                                 Wp_m1, b_m1, Wp_m2, b_m2, agg);
    upd_kernel<<<(NNODES + 63) / 64, 256, 0, stream>>>(h, agg,
                                                       Wp_u1, b_u1, Wp_u2, b_u2, out);
}

// Round 11
// 234.645 us; speedup vs baseline: 1.2441x; 1.1275x over previous
//
#include <hip/hip_runtime.h>
#include <hip/hip_bf16.h>
#include <hip/hip_fp16.h>
#include <cstdint>
#include <cstddef>

#define NNODES 50000
#define NEDGES 800000
#define DF 64
#define KM 192      // msg MLP input dim (3*D)
#define KU 128      // upd MLP input dim (2*D)
#define SROW 264    // LDS row stride in bf16 elems (528 B, 16B-aligned; proven in r3/r6)

typedef __bf16 bf16_t;
typedef __bf16 bf16x8 __attribute__((ext_vector_type(8)));
typedef __bf16 bf16x4 __attribute__((ext_vector_type(4)));
typedef float  f32x4  __attribute__((ext_vector_type(4)));
typedef _Float16 f16x2 __attribute__((ext_vector_type(2)));

// ---------------------------------------------------------------------------
// Weight packing: W[K][N] fp32 row-major -> bf16 MFMA B-fragments.
// Fragment (kblk, ct): lane l, elem j holds W[kblk*32 + (l>>4)*8 + j][ct*16 + (l&15)]
// Flat: ((kblk*(N/16) + ct)*64 + l)*8 + j.
// Segments: Wm1 @0 (49152), Wm2 @49152 (16384), Wu1 @65536 (32768), Wu2 @98304 (16384).
// ---------------------------------------------------------------------------
__global__ void prep_kernel(const float* __restrict__ Wm1, const float* __restrict__ Wm2,
                            const float* __restrict__ Wu1, const float* __restrict__ Wu2,
                            bf16_t* __restrict__ wp)
{
    int idx = blockIdx.x * 256 + threadIdx.x;
    const float* src; int N; int off; int local;
    if (idx < 49152)       { src = Wm1; N = 256; off = 0;     local = idx; }
    else if (idx < 65536)  { src = Wm2; N = 64;  off = 49152; local = idx - 49152; }
    else if (idx < 98304)  { src = Wu1; N = 256; off = 65536; local = idx - 65536; }
    else if (idx < 114688) { src = Wu2; N = 64;  off = 98304; local = idx - 98304; }
    else return;
    int j    = local & 7;
    int l    = (local >> 3) & 63;
    int frag = local >> 9;
    int nct  = N >> 4;
    int kblk = frag / nct;
    int ct   = frag - kblk * nct;
    int k = kblk * 32 + (l >> 4) * 8 + j;
    int n = ct * 16 + (l & 15);
    wp[off + local] = (bf16_t)src[(size_t)k * N + n];
}

__device__ __forceinline__ void st_bf16x4(bf16_t* p, float4 v) {
    bf16x4 bv;
    bv[0] = (bf16_t)v.x; bv[1] = (bf16_t)v.y; bv[2] = (bf16_t)v.z; bv[3] = (bf16_t)v.w;
    *reinterpret_cast<bf16x4*>(p) = bv;
}

// ---------------------------------------------------------------------------
// Message kernel: r6's proven body (128 edges/block, 512 threads, 8 waves;
// layer1 N-split 16-col-pair/wave over all 128 edges; layer2 64 rows x 16 cols).
// ONLY the scatter differs (template):
//   H2=true : packed f16 atomics via __builtin_amdgcn_global_atomic_fadd_v2f16
//             (global_atomic_pk_add_f16). Pair adjacent columns via one
//             __shfl_xor(1): 8 pk-atomics/thread (was 16 f32).
//             51.2M -> 25.6M atomic ops, 205 -> 102 MB atomic bytes.
//   H2=false: legacy fp32 atomics into f32 agg (ws too small; agg aliases out —
//             alias-safe per upd_kernel structure).
// ---------------------------------------------------------------------------
template<bool H2>
__global__ __launch_bounds__(512, 4)
void msg_kernel(const float* __restrict__ h, const float* __restrict__ efeat,
                const int* __restrict__ snd, const int* __restrict__ rcv,
                const bf16_t* __restrict__ Wp1, const float* __restrict__ b1,
                const bf16_t* __restrict__ Wp2, const float* __restrict__ b2,
                void* __restrict__ aggv)
{
    __shared__ bf16_t s_buf[128 * SROW];   // 67584 B
    __shared__ int s_snd[128];
    __shared__ int s_rcv[128];

    const int t  = threadIdx.x;
    const int e0 = blockIdx.x * 128;

    if (t < 128)      s_snd[t]       = snd[e0 + t];
    else if (t < 256) s_rcv[t - 128] = rcv[e0 + t - 128];

    // e-segment (no idx dependency): 128 rows x 16 float4, 4 iters of 512
    #pragma unroll
    for (int it = 0; it < 4; ++it) {
        int i = t + it * 512; int row = i >> 4; int col = (i & 15) * 4;
        float4 v = *reinterpret_cast<const float4*>(efeat + (size_t)(e0 + row) * DF + col);
        st_bf16x4(&s_buf[row * SROW + col], v);
    }
    __syncthreads();   // idx visible (e-writes touch a disjoint LDS region)

    #pragma unroll
    for (int it = 0; it < 4; ++it) {
        int i = t + it * 512; int row = i >> 4; int col = (i & 15) * 4;
        float4 v = *reinterpret_cast<const float4*>(h + (size_t)s_snd[row] * DF + col);
        st_bf16x4(&s_buf[row * SROW + DF + col], v);
    }
    #pragma unroll
    for (int it = 0; it < 4; ++it) {
        int i = t + it * 512; int row = i >> 4; int col = (i & 15) * 4;
        float4 v = *reinterpret_cast<const float4*>(h + (size_t)s_rcv[row] * DF + col);
        st_bf16x4(&s_buf[row * SROW + 2 * DF + col], v);
    }
    __syncthreads();

    const int w = t >> 6;      // wave 0..7
    const int l = t & 63;
    const int q = l >> 4;
    const int r = l & 15;

    // ---- layer 1: M=128 (8 A-frags), N=32 per wave (ct = w*2, w*2+1) ----
    f32x4 acc[2][8];
    #pragma unroll
    for (int g = 0; g < 2; ++g)
        #pragma unroll
        for (int am = 0; am < 8; ++am) acc[g][am] = (f32x4){0.f, 0.f, 0.f, 0.f};

    #pragma unroll
    for (int kb = 0; kb < 6; ++kb) {
        bf16x8 b0 = *reinterpret_cast<const bf16x8*>(Wp1 + ((size_t)(kb * 16 + w * 2 + 0) * 64 + l) * 8);
        bf16x8 b1f = *reinterpret_cast<const bf16x8*>(Wp1 + ((size_t)(kb * 16 + w * 2 + 1) * 64 + l) * 8);
        #pragma unroll
        for (int am = 0; am < 8; ++am) {
            bf16x8 a = *reinterpret_cast<const bf16x8*>(&s_buf[(am * 16 + r) * SROW + kb * 32 + q * 8]);
            acc[0][am] = __builtin_amdgcn_mfma_f32_16x16x32_bf16(a, b0,  acc[0][am], 0, 0, 0);
            acc[1][am] = __builtin_amdgcn_mfma_f32_16x16x32_bf16(a, b1f, acc[1][am], 0, 0, 0);
        }
    }
    __syncthreads();   // all waves done reading the input tile

    // bias + relu -> c1 into s_buf (row = edge, col = hidden unit)
    #pragma unroll
    for (int g = 0; g < 2; ++g) {
        const int col1 = (w * 2 + g) * 16 + r;
        const float bias1 = b1[col1];
        #pragma unroll
        for (int am = 0; am < 8; ++am)
            #pragma unroll
            for (int j = 0; j < 4; ++j)
                s_buf[(am * 16 + q * 4 + j) * SROW + col1] =
                    (bf16_t)fmaxf(acc[g][am][j] + bias1, 0.f);
    }
    __syncthreads();   // c1 complete

    // ---- layer 2: wave w -> rows [m2*64, m2*64+64), cols [ct2*16, ct2*16+16) ----
    const int m2  = w >> 2;
    const int ct2 = w & 3;
    f32x4 acc2[4];
    #pragma unroll
    for (int am = 0; am < 4; ++am) acc2[am] = (f32x4){0.f, 0.f, 0.f, 0.f};

    #pragma unroll
    for (int kb = 0; kb < 8; ++kb) {
        bf16x8 b = *reinterpret_cast<const bf16x8*>(Wp2 + ((size_t)(kb * 4 + ct2) * 64 + l) * 8);
        #pragma unroll
        for (int am = 0; am < 4; ++am) {
            bf16x8 a = *reinterpret_cast<const bf16x8*>(&s_buf[(m2 * 64 + am * 16 + r) * SROW + kb * 32 + q * 8]);
            acc2[am] = __builtin_amdgcn_mfma_f32_16x16x32_bf16(a, b, acc2[am], 0, 0, 0);
        }
    }

    if constexpr (H2) {
        // packed-f16 scatter: lane pair (r even/odd) covers rows q*4+{0..3} x cols {cp,cp+1}.
        // After shfl_xor(1): even lane emits rows q*4+{0,1}, odd lane rows q*4+{2,3}.
        _Float16* aggh = (_Float16*)aggv;
        const int  cp  = ct2 * 16 + (r & ~1);
        const bool odd = (r & 1);
        const float blo = b2[cp], bhi = b2[cp + 1];
        #pragma unroll
        for (int am = 0; am < 4; ++am) {
            float v0 = acc2[am][0], v1 = acc2[am][1], v2 = acc2[am][2], v3 = acc2[am][3];
            float p0 = __shfl_xor(v0, 1), p1 = __shfl_xor(v1, 1);
            float p2 = __shfl_xor(v2, 1), p3 = __shfl_xor(v3, 1);
            float loA = odd ? p2 : v0, hiA = odd ? v2 : p0;
            float loB = odd ? p3 : v1, hiB = odd ? v3 : p1;
            int jbase = odd ? 2 : 0;
            int erowA = m2 * 64 + am * 16 + q * 4 + jbase;
            f16x2 hA = { (_Float16)(loA + blo), (_Float16)(hiA + bhi) };
            f16x2 hB = { (_Float16)(loB + blo), (_Float16)(hiB + bhi) };
            __builtin_amdgcn_global_atomic_fadd_v2f16(
                (f16x2*)(aggh + (size_t)s_rcv[erowA]     * DF + cp), hA);
            __builtin_amdgcn_global_atomic_fadd_v2f16(
                (f16x2*)(aggh + (size_t)s_rcv[erowA + 1] * DF + cp), hB);
        }
    } else {
        float* agg = (float*)aggv;
        const float bias2 = b2[ct2 * 16 + r];
        #pragma unroll
        for (int am = 0; am < 4; ++am)
            #pragma unroll
            for (int j = 0; j < 4; ++j) {
                int erow = m2 * 64 + am * 16 + q * 4 + j;
                atomicAdd(agg + (size_t)s_rcv[erow] * DF + ct2 * 16 + r, acc2[am][j] + bias2);
            }
    }
}

// ---------------------------------------------------------------------------
// Node-update kernel: r3/r6's proven body; gather reads agg as f16 (H2) or
// f32 (fallback, alias-safe when agg==out: reads precede all stores).
// ---------------------------------------------------------------------------
template<bool H2>
__global__ __launch_bounds__(256, 4)
void upd_kernel(const float* __restrict__ h, const void* __restrict__ aggv,
                const bf16_t* __restrict__ Wp1, const float* __restrict__ b1,
                const bf16_t* __restrict__ Wp2, const float* __restrict__ b2,
                float* __restrict__ out)
{
    __shared__ bf16_t s_buf[64 * SROW];

    const int t  = threadIdx.x;
    const int n0 = blockIdx.x * 64;

    // gather u_in = [h | agg] : 64 rows x 128 cols
    if constexpr (H2) {
        const _Float16* aggh = (const _Float16*)aggv;
        #pragma unroll
        for (int it = 0; it < 4; ++it) {            // h: 64 rows x 16 float4
            int i = t + it * 256; int nn = i >> 4; int col = (i & 15) * 4;
            int node = n0 + nn;
            float4 v = {0.f, 0.f, 0.f, 0.f};
            if (node < NNODES) v = *reinterpret_cast<const float4*>(h + (size_t)node * DF + col);
            st_bf16x4(&s_buf[nn * SROW + col], v);
        }
        #pragma unroll
        for (int it = 0; it < 4; ++it) {            // agg: 64 rows x 16 groups of 4 f16
            int i = t + it * 256; int nn = i >> 4; int col = (i & 15) * 4;
            int node = n0 + nn;
            float4 v = {0.f, 0.f, 0.f, 0.f};
            if (node < NNODES) {
                f16x2 h01 = *reinterpret_cast<const f16x2*>(aggh + (size_t)node * DF + col);
                f16x2 h23 = *reinterpret_cast<const f16x2*>(aggh + (size_t)node * DF + col + 2);
                v.x = (float)h01[0]; v.y = (float)h01[1];
                v.z = (float)h23[0]; v.w = (float)h23[1];
            }
            st_bf16x4(&s_buf[nn * SROW + DF + col], v);
        }
    } else {
        const float* agg = (const float*)aggv;
        #pragma unroll
        for (int it = 0; it < 8; ++it) {
            int i = t + it * 256; int nn = i >> 5; int col = (i & 31) * 4;
            int node = n0 + nn;
            float4 v = {0.f, 0.f, 0.f, 0.f};
            if (node < NNODES) {
                const float* srcp = (col < DF) ? (h + (size_t)node * DF + col)
                                               : (agg + (size_t)node * DF + (col - DF));
                v = *reinterpret_cast<const float4*>(srcp);
            }
            st_bf16x4(&s_buf[nn * SROW + col], v);
        }
    }
    __syncthreads();

    const int w = t >> 6;
    const int l = t & 63;
    const int q = l >> 4;
    const int r = l & 15;

    f32x4 acc[4][4];
    #pragma unroll
    for (int g = 0; g < 4; ++g)
        #pragma unroll
        for (int am = 0; am < 4; ++am) acc[g][am] = (f32x4){0.f, 0.f, 0.f, 0.f};

    #pragma unroll
    for (int kb = 0; kb < 4; ++kb) {
        bf16x8 a[4];
        #pragma unroll
        for (int am = 0; am < 4; ++am)
            a[am] = *reinterpret_cast<const bf16x8*>(&s_buf[(am * 16 + r) * SROW + kb * 32 + q * 8]);
        #pragma unroll
        for (int g = 0; g < 4; ++g) {
            int ct = w * 4 + g;
            bf16x8 b = *reinterpret_cast<const bf16x8*>(Wp1 + ((size_t)(kb * 16 + ct) * 64 + l) * 8);
            #pragma unroll
            for (int am = 0; am < 4; ++am)
                acc[g][am] = __builtin_amdgcn_mfma_f32_16x16x32_bf16(a[am], b, acc[g][am], 0, 0, 0);
        }
    }
    __syncthreads();

    #pragma unroll
    for (int g = 0; g < 4; ++g) {
        int col = (w * 4 + g) * 16 + r;
        float bias = b1[col];
        #pragma unroll
        for (int am = 0; am < 4; ++am)
            #pragma unroll
            for (int j = 0; j < 4; ++j)
                s_buf[(am * 16 + q * 4 + j) * SROW + col] =
                    (bf16_t)fmaxf(acc[g][am][j] + bias, 0.f);
    }
    __syncthreads();

    f32x4 acc2[4];
    #pragma unroll
    for (int am = 0; am < 4; ++am) acc2[am] = (f32x4){0.f, 0.f, 0.f, 0.f};

    #pragma unroll
    for (int kb = 0; kb < 8; ++kb) {
        bf16x8 a[4];
        #pragma unroll
        for (int am = 0; am < 4; ++am)
            a[am] = *reinterpret_cast<const bf16x8*>(&s_buf[(am * 16 + r) * SROW + kb * 32 + q * 8]);
        bf16x8 b = *reinterpret_cast<const bf16x8*>(Wp2 + ((size_t)(kb * 4 + w) * 64 + l) * 8);
        #pragma unroll
        for (int am = 0; am < 4; ++am)
            acc2[am] = __builtin_amdgcn_mfma_f32_16x16x32_bf16(a[am], b, acc2[am], 0, 0, 0);
    }

    // residual store: out = h + dh  (col = w*16 + r)
    float bias2 = b2[w * 16 + r];
    #pragma unroll
    for (int am = 0; am < 4; ++am)
        #pragma unroll
        for (int j = 0; j < 4; ++j) {
            int node = n0 + am * 16 + q * 4 + j;
            if (node < NNODES) {
                int col = w * 16 + r;
                out[(size_t)node * DF + col] =
                    h[(size_t)node * DF + col] + acc2[am][j] + bias2;
            }
        }
}

extern "C" void kernel_launch(void* const* d_in, const int* in_sizes, int n_in,
                              void* d_out, int out_size, void* d_ws, size_t ws_size,
                              hipStream_t stream)
{
    const float* h    = (const float*)d_in[0];
    const float* e    = (const float*)d_in[1];
    const int*   snd  = (const int*)d_in[2];
    const int*   rcv  = (const int*)d_in[3];
    const float* W_m1 = (const float*)d_in[4];
    const float* b_m1 = (const float*)d_in[5];
    const float* W_m2 = (const float*)d_in[6];
    const float* b_m2 = (const float*)d_in[7];
    const float* W_u1 = (const float*)d_in[8];
    const float* b_u1 = (const float*)d_in[9];
    const float* W_u2 = (const float*)d_in[10];
    const float* b_u2 = (const float*)d_in[11];
    float* out = (float*)d_out;

    const size_t aggh_bytes = (size_t)NNODES * DF * sizeof(_Float16);  // 6.4 MB
    const size_t wp_bytes   = 114688 * sizeof(bf16_t);                 // 229 KB

    const bool useH2 = (ws_size >= aggh_bytes + wp_bytes);

    void*   aggv;
    bf16_t* wp;
    size_t  agg_clear;
    if (useH2) {
        aggv = d_ws;
        wp   = (bf16_t*)((char*)d_ws + aggh_bytes);
        agg_clear = aggh_bytes;
    } else {
        aggv = out;                       // legacy alias-safe f32 path
        wp   = (bf16_t*)d_ws;
        agg_clear = (size_t)NNODES * DF * sizeof(float);
    }

    bf16_t* Wp_m1 = wp;
    bf16_t* Wp_m2 = wp + 49152;
    bf16_t* Wp_u1 = wp + 65536;
    bf16_t* Wp_u2 = wp + 98304;

    prep_kernel<<<448, 256, 0, stream>>>(W_m1, W_m2, W_u1, W_u2, wp);
    (void)hipMemsetAsync(aggv, 0, agg_clear, stream);

    if (useH2) {
        msg_kernel<true><<<NEDGES / 128, 512, 0, stream>>>(h, e, snd, rcv,
                                                           Wp_m1, b_m1, Wp_m2, b_m2, aggv);
        upd_kernel<true><<<(NNODES + 63) / 64, 256, 0, stream>>>(h, aggv,
                                                                 Wp_u1, b_u1, Wp_u2, b_u2, out);
    } else {
        msg_kernel<false><<<NEDGES / 128, 512, 0, stream>>>(h, e, snd, rcv,
                                                            Wp_m1, b_m1, Wp_m2, b_m2, aggv);
        upd_kernel<false><<<(NNODES + 63) / 64, 256, 0, stream>>>(h, aggv,
                                                                  Wp_u1, b_u1, Wp_u2, b_u2, out);
    }
}